// Round 1
// baseline (2773.628 us; speedup 1.0000x reference)
//
#include <hip/hip_runtime.h>
#include <math.h>

#define TT 4096
#define BB 2
#define MMDIM 256
#define RTOT 8192

// ---------------------------------------------------------------------------
// Generic f32 GEMM: C[R][N] = A[R][K] @ W[N][K]^T + bias, optional *sigmoid(gate)
// Tile 64x64, BK=16, 256 threads, 4x4 micro. Transposed LDS staging so the
// inner loop reads b128 fragments. Requires K % 4 == 0 and 16B-aligned rows
// (true for K = 1024 / 256).
// ---------------------------------------------------------------------------
template<int WITH_GATE>
__global__ __launch_bounds__(256) void gemm_f32(
    const float* __restrict__ A, const float* __restrict__ W,
    const float* __restrict__ bias, const float* __restrict__ gate,
    float* __restrict__ C, int K, int N)
{
    __shared__ float As[16][68];
    __shared__ float Ws[16][68];
    const int tid = threadIdx.x;
    const int tx = tid & 15, ty = tid >> 4;
    const int r0 = blockIdx.x * 64, c0 = blockIdx.y * 64;
    const int lr = tid >> 2;          // 0..63
    const int lk = (tid & 3) << 2;    // 0,4,8,12

    float acc[4][4] = {};

    for (int k0 = 0; k0 < K; k0 += 16) {
        float4 av = *(const float4*)&A[(size_t)(r0 + lr) * K + k0 + lk];
        float4 wv = *(const float4*)&W[(size_t)(c0 + lr) * K + k0 + lk];
        As[lk + 0][lr] = av.x; As[lk + 1][lr] = av.y;
        As[lk + 2][lr] = av.z; As[lk + 3][lr] = av.w;
        Ws[lk + 0][lr] = wv.x; Ws[lk + 1][lr] = wv.y;
        Ws[lk + 2][lr] = wv.z; Ws[lk + 3][lr] = wv.w;
        __syncthreads();
        #pragma unroll
        for (int kk = 0; kk < 16; ++kk) {
            float4 a = *(const float4*)&As[kk][ty * 4];
            float4 b = *(const float4*)&Ws[kk][tx * 4];
            acc[0][0] += a.x * b.x; acc[0][1] += a.x * b.y; acc[0][2] += a.x * b.z; acc[0][3] += a.x * b.w;
            acc[1][0] += a.y * b.x; acc[1][1] += a.y * b.y; acc[1][2] += a.y * b.z; acc[1][3] += a.y * b.w;
            acc[2][0] += a.z * b.x; acc[2][1] += a.z * b.y; acc[2][2] += a.z * b.z; acc[2][3] += a.z * b.w;
            acc[3][0] += a.w * b.x; acc[3][1] += a.w * b.y; acc[3][2] += a.w * b.z; acc[3][3] += a.w * b.w;
        }
        __syncthreads();
    }

    float g = 1.f;
    if (WITH_GATE) g = 1.f / (1.f + expf(-gate[0]));
    #pragma unroll
    for (int i = 0; i < 4; ++i) {
        int row = r0 + ty * 4 + i;
        float4 o;
        o.x = (acc[i][0] + bias[c0 + tx * 4 + 0]) * g;
        o.y = (acc[i][1] + bias[c0 + tx * 4 + 1]) * g;
        o.z = (acc[i][2] + bias[c0 + tx * 4 + 2]) * g;
        o.w = (acc[i][3] + bias[c0 + tx * 4 + 3]) * g;
        *(float4*)&C[(size_t)row * N + c0 + tx * 4] = o;
    }
}

// ---------------------------------------------------------------------------
// h GEMM with fused si = concat(mu, -log(max(lam,1e-6)), pi) generator.
// K = 2055 (tail-guarded, scalar staging since rows are not 16B-aligned).
// ---------------------------------------------------------------------------
__device__ __forceinline__ float si_elem(const float* mu, const float* lam,
                                         const float* pi, int i, int kk)
{
    if (kk < 1024) return mu[(size_t)i * 1024 + kk];
    if (kk < 2048) {
        float l = lam[(size_t)i * 1024 + (kk - 1024)];
        return -logf(fmaxf(l, 1e-6f));
    }
    if (kk < 2055) return pi[(size_t)i * 7 + (kk - 2048)];
    return 0.f;
}

__global__ __launch_bounds__(256) void gemm_si(
    const float* __restrict__ mu, const float* __restrict__ lam,
    const float* __restrict__ pi, const float* __restrict__ W,
    const float* __restrict__ bias, float* __restrict__ C, int K, int N)
{
    __shared__ float As[16][68];
    __shared__ float Ws[16][68];
    const int tid = threadIdx.x;
    const int tx = tid & 15, ty = tid >> 4;
    const int r0 = blockIdx.x * 64, c0 = blockIdx.y * 64;
    const int lr = tid >> 2;
    const int lk = (tid & 3) << 2;

    float acc[4][4] = {};

    for (int k0 = 0; k0 < K; k0 += 16) {
        #pragma unroll
        for (int i = 0; i < 4; ++i) {
            int kk = k0 + lk + i;
            As[lk + i][lr] = si_elem(mu, lam, pi, r0 + lr, kk);
            Ws[lk + i][lr] = (kk < K) ? W[(size_t)(c0 + lr) * K + kk] : 0.f;
        }
        __syncthreads();
        #pragma unroll
        for (int kk = 0; kk < 16; ++kk) {
            float4 a = *(const float4*)&As[kk][ty * 4];
            float4 b = *(const float4*)&Ws[kk][tx * 4];
            acc[0][0] += a.x * b.x; acc[0][1] += a.x * b.y; acc[0][2] += a.x * b.z; acc[0][3] += a.x * b.w;
            acc[1][0] += a.y * b.x; acc[1][1] += a.y * b.y; acc[1][2] += a.y * b.z; acc[1][3] += a.y * b.w;
            acc[2][0] += a.z * b.x; acc[2][1] += a.z * b.y; acc[2][2] += a.z * b.z; acc[2][3] += a.z * b.w;
            acc[3][0] += a.w * b.x; acc[3][1] += a.w * b.y; acc[3][2] += a.w * b.z; acc[3][3] += a.w * b.w;
        }
        __syncthreads();
    }

    #pragma unroll
    for (int i = 0; i < 4; ++i) {
        int row = r0 + ty * 4 + i;
        float4 o;
        o.x = acc[i][0] + bias[c0 + tx * 4 + 0];
        o.y = acc[i][1] + bias[c0 + tx * 4 + 1];
        o.z = acc[i][2] + bias[c0 + tx * 4 + 2];
        o.w = acc[i][3] + bias[c0 + tx * 4 + 3];
        *(float4*)&C[(size_t)row * N + c0 + tx * 4] = o;
    }
}

// ---------------------------------------------------------------------------
// s gate + kappa' precompute. One wave per token.
// kap[t][l] = (1-s) * exp(-0.5*(l - 12 s)^2) / Z   (l = 0..12), sb[t] = s.
// ---------------------------------------------------------------------------
__global__ __launch_bounds__(256) void s_kernel(
    const float* __restrict__ h, const float* __restrict__ Ws2,
    const float* __restrict__ bs2, float* __restrict__ sb,
    float* __restrict__ kap)
{
    const int tid = threadIdx.x;
    const int wave = tid >> 6, lane = tid & 63;
    const int t = blockIdx.x * 4 + wave;

    float4 hv = *(const float4*)&h[(size_t)t * MMDIM + lane * 4];
    float4 wv = *(const float4*)&Ws2[lane * 4];
    float p = 0.f;
    p += (hv.x / (1.f + expf(-hv.x))) * wv.x;
    p += (hv.y / (1.f + expf(-hv.y))) * wv.y;
    p += (hv.z / (1.f + expf(-hv.z))) * wv.z;
    p += (hv.w / (1.f + expf(-hv.w))) * wv.w;
    #pragma unroll
    for (int o = 32; o; o >>= 1) p += __shfl_xor(p, o);

    float z = p + bs2[0];
    float s = 1.f / (1.f + expf(-z));
    float c = s * 12.f;
    float Z = 0.f;
    #pragma unroll
    for (int l = 0; l < 13; ++l) {
        float d = (float)l - c;
        Z += expf(-0.5f * d * d);
    }
    Z = fmaxf(Z, 1e-8f);
    if (lane < 13) {
        float d = (float)lane - c;
        kap[(size_t)t * 16 + lane] = (1.f - s) * expf(-0.5f * d * d) / Z;
    }
    if (lane == 0) sb[t] = s;
}

// ---------------------------------------------------------------------------
// Scratch attention (S=8) + ctx init: ctx[t] = s * softmax(sq.scratch/16) @ scratch
// One wave per token.
// ---------------------------------------------------------------------------
__global__ __launch_bounds__(256) void scratch_kernel(
    const float* __restrict__ sq, const float* __restrict__ scr,
    const float* __restrict__ sb, float* __restrict__ ctx)
{
    const int tid = threadIdx.x;
    const int wave = tid >> 6, lane = tid & 63;
    const int t = blockIdx.x * 4 + wave;

    float4 qv = *(const float4*)&sq[(size_t)t * MMDIM + lane * 4];
    float4 fr[8];
    float sc[8];
    #pragma unroll
    for (int s = 0; s < 8; ++s) {
        fr[s] = *(const float4*)&scr[s * MMDIM + lane * 4];
        sc[s] = qv.x * fr[s].x + qv.y * fr[s].y + qv.z * fr[s].z + qv.w * fr[s].w;
    }
    #pragma unroll
    for (int s = 0; s < 8; ++s) {
        #pragma unroll
        for (int o = 32; o; o >>= 1) sc[s] += __shfl_xor(sc[s], o);
        sc[s] *= 0.0625f;
    }
    float mx = sc[0];
    #pragma unroll
    for (int s = 1; s < 8; ++s) mx = fmaxf(mx, sc[s]);
    float sum = 0.f;
    #pragma unroll
    for (int s = 0; s < 8; ++s) { sc[s] = expf(sc[s] - mx); sum += sc[s]; }
    float inv = 1.f / sum;
    float blend = sb[t];
    float4 o = {0, 0, 0, 0};
    #pragma unroll
    for (int s = 0; s < 8; ++s) {
        float pp = sc[s] * inv;
        o.x += pp * fr[s].x; o.y += pp * fr[s].y;
        o.z += pp * fr[s].z; o.w += pp * fr[s].w;
    }
    o.x *= blend; o.y *= blend; o.z *= blend; o.w *= blend;
    *(float4*)&ctx[(size_t)t * MMDIM + lane * 4] = o;
}

// ---------------------------------------------------------------------------
// Tree build. Levels 1..12 of the weighted pairwise tree (k or v per blockIdx.y),
// batch per blockIdx.z, 64-dim m-chunk per blockIdx.x. w-tree built in LDS.
// ---------------------------------------------------------------------------
__global__ __launch_bounds__(256) void tree_kernel(
    const float* __restrict__ kleaf, const float* __restrict__ vleaf,
    const float* __restrict__ pw, float* __restrict__ ktree,
    float* __restrict__ vtree)
{
    __shared__ float wb[8192];
    const int tid = threadIdx.x;
    const int mc = blockIdx.x;
    const int isv = blockIdx.y;
    const int b = blockIdx.z;

    for (int t = tid; t < 4096; t += 256) wb[t] = pw[b * 4096 + t];
    __syncthreads();
    { // w-tree
        int src = 0, dst = 4096, n = 4096;
        while (n > 1) {
            int nout = n >> 1;
            for (int j = tid; j < nout; j += 256)
                wb[dst + j] = wb[src + 2 * j] + wb[src + 2 * j + 1] + 1e-8f;
            __syncthreads();
            src = dst; dst += nout; n = nout;
        }
    }

    const float* leaf = isv ? vleaf : kleaf;
    float* tout = isv ? vtree : ktree;
    const int m = mc * 64 + (tid & 63);
    const int j0 = tid >> 6;

    const float* in = leaf + (size_t)b * 4096 * MMDIM;
    int src = 0, dst = 4096, n = 4096, treeoff = 0;
    while (n > 1) {
        int nout = n >> 1;
        float* out = tout + (size_t)(b * 4095 + treeoff) * MMDIM;
        for (int j = j0; j < nout; j += 4) {
            float w1 = wb[src + 2 * j], w2 = wb[src + 2 * j + 1];
            float tw = wb[dst + j];
            float x1 = in[(size_t)(2 * j) * MMDIM + m];
            float x2 = in[(size_t)(2 * j + 1) * MMDIM + m];
            out[(size_t)j * MMDIM + m] = (w1 * x1 + w2 * x2) / tw;
        }
        __syncthreads();
        in = out; src = dst; dst += nout; treeoff += nout; n = nout;
    }
}

// ---------------------------------------------------------------------------
// Fused retrieval over all 13 levels: masked scores, streaming top-4 (tie-break:
// lower index), softmax over the 4, kappa'-weighted V gather, register ctx
// accumulation, single RMW of ctx at the end.
// Block: 256 threads = 32 q-rows x 128-node chunks, 4x4 micro (ty 0..7, tx 0..31).
// ---------------------------------------------------------------------------
__device__ __forceinline__ bool beats(float v, int id, float v2, int id2)
{
    return (v > v2) || (v == v2 && id < id2);
}

__device__ __forceinline__ void ins4(float v, int id, float tv[4], int ti[4])
{
    if (!beats(v, id, tv[3], ti[3])) return;
    tv[3] = v; ti[3] = id;
    #pragma unroll
    for (int s = 3; s > 0; --s) {
        if (beats(tv[s], ti[s], tv[s - 1], ti[s - 1])) {
            float fv = tv[s]; tv[s] = tv[s - 1]; tv[s - 1] = fv;
            int iv = ti[s]; ti[s] = ti[s - 1]; ti[s - 1] = iv;
        }
    }
}

__global__ __launch_bounds__(256) void retrieve_kernel(
    const float* __restrict__ q, const float* __restrict__ kl0,
    const float* __restrict__ vl0, const float* __restrict__ ktree,
    const float* __restrict__ vtree, const float* __restrict__ kap,
    float* __restrict__ ctx)
{
    __shared__ float qs[256][36];    // [m][row], padded
    __shared__ float ks[64][132];    // [m within chunk][col], padded

    const int tid = threadIdx.x;
    const int tx = tid & 31;   // col group (4 cols each -> 128)
    const int ty = tid >> 5;   // row group (4 rows each -> 32)
    const int r0 = blockIdx.x * 32;
    const int b = r0 >> 12;
    const int t0 = r0 & 4095;

    // stage q transposed: qs[m][row]
    #pragma unroll
    for (int g = 0; g < 8; ++g) {
        int e = tid + g * 256;        // 0..2047
        int row = e >> 6;
        int qd = e & 63;
        float4 qv = *(const float4*)&q[(size_t)(r0 + row) * MMDIM + qd * 4];
        qs[qd * 4 + 0][row] = qv.x; qs[qd * 4 + 1][row] = qv.y;
        qs[qd * 4 + 2][row] = qv.z; qs[qd * 4 + 3][row] = qv.w;
    }
    __syncthreads();

    float ctxr[4][8] = {};   // [row i][m slice], m = tx*8 + mm

    for (int l = 0; l <= 12; ++l) {
        const int n = TT >> l;
        const float* Kb;
        const float* Vb;
        if (l == 0) {
            Kb = kl0 + (size_t)b * TT * MMDIM;
            Vb = vl0 + (size_t)b * TT * MMDIM;
        } else {
            int off = TT - (8192 >> l);
            Kb = ktree + (size_t)(b * 4095 + off) * MMDIM;
            Vb = vtree + (size_t)(b * 4095 + off) * MMDIM;
        }
        const int nvalid = min(n, t0 + 32);

        float tv[4][4];
        int ti[4][4];
        #pragma unroll
        for (int i = 0; i < 4; ++i)
            #pragma unroll
            for (int s = 0; s < 4; ++s) { tv[i][s] = -INFINITY; ti[i][s] = 0x7fffffff; }

        for (int c0 = 0; c0 < nvalid; c0 += 128) {
            float acc[4][4] = {};
            for (int mc = 0; mc < 4; ++mc) {
                // stage ks: 128 cols x 64 m
                #pragma unroll
                for (int g = 0; g < 8; ++g) {
                    int e = tid + g * 256;       // 0..2047
                    int col = e >> 4;            // 0..127
                    int qd = e & 15;             // quad in m
                    float4 kv = {0, 0, 0, 0};
                    if (c0 + col < n)
                        kv = *(const float4*)&Kb[(size_t)(c0 + col) * MMDIM + mc * 64 + qd * 4];
                    ks[qd * 4 + 0][col] = kv.x; ks[qd * 4 + 1][col] = kv.y;
                    ks[qd * 4 + 2][col] = kv.z; ks[qd * 4 + 3][col] = kv.w;
                }
                __syncthreads();
                #pragma unroll 16
                for (int mm = 0; mm < 64; ++mm) {
                    float4 a = *(const float4*)&qs[mc * 64 + mm][ty * 4];
                    float4 bb = *(const float4*)&ks[mm][tx * 4];
                    acc[0][0] += a.x * bb.x; acc[0][1] += a.x * bb.y; acc[0][2] += a.x * bb.z; acc[0][3] += a.x * bb.w;
                    acc[1][0] += a.y * bb.x; acc[1][1] += a.y * bb.y; acc[1][2] += a.y * bb.z; acc[1][3] += a.y * bb.w;
                    acc[2][0] += a.z * bb.x; acc[2][1] += a.z * bb.y; acc[2][2] += a.z * bb.z; acc[2][3] += a.z * bb.w;
                    acc[3][0] += a.w * bb.x; acc[3][1] += a.w * bb.y; acc[3][2] += a.w * bb.z; acc[3][3] += a.w * bb.w;
                }
                __syncthreads();
            }
            // insert candidates (mask: col <= t_row, col < n)
            #pragma unroll
            for (int i = 0; i < 4; ++i) {
                int trow = t0 + ty * 4 + i;
                #pragma unroll
                for (int j = 0; j < 4; ++j) {
                    int c = c0 + tx * 4 + j;
                    float v = (c < n && c <= trow) ? acc[i][j] * 0.0625f : -INFINITY;
                    ins4(v, c, tv[i], ti[i]);
                }
            }
        }

        // butterfly merge of top-4 across the 32 tx lanes
        #pragma unroll
        for (int off = 1; off < 32; off <<= 1) {
            #pragma unroll
            for (int i = 0; i < 4; ++i) {
                float ov[4]; int oi[4];
                #pragma unroll
                for (int s = 0; s < 4; ++s) {
                    ov[s] = __shfl_xor(tv[i][s], off);
                    oi[s] = __shfl_xor(ti[i][s], off);
                }
                #pragma unroll
                for (int s = 0; s < 4; ++s) ins4(ov[s], oi[s], tv[i], ti[i]);
            }
        }

        // softmax over the 4 + kappa'-weighted V gather into ctx registers
        #pragma unroll
        for (int i = 0; i < 4; ++i) {
            float m0 = tv[i][0];
            float e0 = expf(tv[i][0] - m0);
            float e1 = expf(tv[i][1] - m0);
            float e2 = expf(tv[i][2] - m0);
            float e3 = expf(tv[i][3] - m0);
            float sum = e0 + e1 + e2 + e3;
            float kp = kap[(size_t)(r0 + ty * 4 + i) * 16 + l];
            float scl = kp / sum;
            float ps[4] = {e0 * scl, e1 * scl, e2 * scl, e3 * scl};
            #pragma unroll
            for (int s = 0; s < 4; ++s) {
                if (ps[s] > 0.f) {
                    const float* vr = Vb + (size_t)ti[i][s] * MMDIM + tx * 8;
                    float4 va = *(const float4*)vr;
                    float4 vb2 = *(const float4*)(vr + 4);
                    ctxr[i][0] += ps[s] * va.x;  ctxr[i][1] += ps[s] * va.y;
                    ctxr[i][2] += ps[s] * va.z;  ctxr[i][3] += ps[s] * va.w;
                    ctxr[i][4] += ps[s] * vb2.x; ctxr[i][5] += ps[s] * vb2.y;
                    ctxr[i][6] += ps[s] * vb2.z; ctxr[i][7] += ps[s] * vb2.w;
                }
            }
        }
    }

    // final RMW into ctx (already holds s*scratch_ctx)
    #pragma unroll
    for (int i = 0; i < 4; ++i) {
        float* cp = ctx + (size_t)(r0 + ty * 4 + i) * MMDIM + tx * 8;
        float4 c1 = *(float4*)cp;
        float4 c2 = *(float4*)(cp + 4);
        c1.x += ctxr[i][0]; c1.y += ctxr[i][1]; c1.z += ctxr[i][2]; c1.w += ctxr[i][3];
        c2.x += ctxr[i][4]; c2.y += ctxr[i][5]; c2.z += ctxr[i][6]; c2.w += ctxr[i][7];
        *(float4*)cp = c1;
        *(float4*)(cp + 4) = c2;
    }
}

// ---------------------------------------------------------------------------
extern "C" void kernel_launch(void* const* d_in, const int* in_sizes, int n_in,
                              void* d_out, int out_size, void* d_ws, size_t ws_size,
                              hipStream_t stream)
{
    const float* mu  = (const float*)d_in[0];
    const float* lam = (const float*)d_in[1];
    const float* pi  = (const float*)d_in[2];
    const float* pw  = (const float*)d_in[3];
    const float* Wq  = (const float*)d_in[4];
    const float* bq  = (const float*)d_in[5];
    const float* Wk  = (const float*)d_in[6];
    const float* bk  = (const float*)d_in[7];
    const float* Wv  = (const float*)d_in[8];
    const float* bv  = (const float*)d_in[9];
    const float* Wo  = (const float*)d_in[10];
    const float* bo  = (const float*)d_in[11];
    const float* Ws1 = (const float*)d_in[12];
    const float* bs1 = (const float*)d_in[13];
    const float* Ws2 = (const float*)d_in[14];
    const float* bs2 = (const float*)d_in[15];
    const float* Wsr = (const float*)d_in[16];
    const float* bsr = (const float*)d_in[17];
    const float* scr = (const float*)d_in[18];
    const float* gate = (const float*)d_in[19];
    float* out = (float*)d_out;

    float* w = (float*)d_ws;
    const size_t RM = (size_t)RTOT * MMDIM;
    float* q_   = w;  w += RM;
    float* k_   = w;  w += RM;
    float* v_   = w;  w += RM;
    float* h_   = w;  w += RM;
    float* sq_  = w;  w += RM;
    float* ctx_ = w;  w += RM;
    float* sb_  = w;  w += RTOT;
    float* kap_ = w;  w += (size_t)RTOT * 16;
    float* kt_  = w;  w += (size_t)BB * 4095 * MMDIM;
    float* vt_  = w;  w += (size_t)BB * 4095 * MMDIM;

    gemm_f32<0><<<dim3(128, 4), 256, 0, stream>>>(mu, Wq, bq, nullptr, q_, 1024, 256);
    gemm_f32<0><<<dim3(128, 4), 256, 0, stream>>>(mu, Wk, bk, nullptr, k_, 1024, 256);
    gemm_f32<0><<<dim3(128, 4), 256, 0, stream>>>(mu, Wv, bv, nullptr, v_, 1024, 256);
    gemm_si<<<dim3(128, 4), 256, 0, stream>>>(mu, lam, pi, Ws1, bs1, h_, 2055, 256);
    s_kernel<<<2048, 256, 0, stream>>>(h_, Ws2, bs2, sb_, kap_);
    gemm_f32<0><<<dim3(128, 4), 256, 0, stream>>>(q_, Wsr, bsr, nullptr, sq_, 256, 256);
    scratch_kernel<<<2048, 256, 0, stream>>>(sq_, scr, sb_, ctx_);
    tree_kernel<<<dim3(4, 2, 2), 256, 0, stream>>>(k_, v_, pw, kt_, vt_);
    retrieve_kernel<<<256, 256, 0, stream>>>(q_, k_, v_, kt_, vt_, kap_, ctx_);
    gemm_f32<1><<<dim3(128, 16), 256, 0, stream>>>(ctx_, Wo, bo, gate, out, 256, 1024);
}